// Round 1
// baseline (88.656 us; speedup 1.0000x reference)
//
#include <hip/hip_runtime.h>

// SDT forward, fp16 MFMA (fp32 accumulate), v2: latency-oriented restructure.
//   - 512 blocks x 256 threads, 16 rows/block -> 2 independent barrier domains/CU
//   - sigmoid+bias+reg fused into GEMM epilogue (register-resident), 4 barriers
//   - wt prefetch depth 2, vt B-frags prefetched into regs during phase 2b
// W^T and value^T stored FRAGMENT-MAJOR (unchanged layout from verified v1):
// MFMA 16x16x32 layouts (HW-verified): A/B^T lane&15->row, (lane>>4)*8->k;
// C/D: col=lane&15, row=(lane>>4)*4+reg.

typedef __attribute__((ext_vector_type(8))) _Float16 half8;
typedef __attribute__((ext_vector_type(4))) _Float16 half4;
typedef __attribute__((ext_vector_type(4))) float floatx4;

constexpr int O = 64;
constexpr int XSTR = 520;   // x-tile LDS row stride (halfs): 1040 B
constexpr int PSTR = 280;   // P_h row stride (halfs): 560 B (16B-aligned)
constexpr int LSTR = 260;   // L_s row stride (floats)

// ---- pre: W^T fp16 frag-major; value^T fp16 frag-major; zero reg ----
// wt layout: block (T*16+c) of 1024 B; lane=(q*16+r16); elem j:
//   wt[(T*16+c)*512 + lane*8 + j] = W[k= c*32+q*8+j][n= T*16+r16]
__global__ __launch_bounds__(256) void sdt_pre(
    const float* __restrict__ Ws, const float* __restrict__ value,
    _Float16* __restrict__ wt, _Float16* __restrict__ vt,
    float* __restrict__ reg_slot)
{
  const int bid = blockIdx.x, t = threadIdx.x;
  if (bid < 64) {                      // W: 8 k-rows per block, coalesced reads
    const int k0 = bid * 8;
    const int n = t;                   // 0..255
    const int T = n >> 4, r = n & 15;
    const int c = k0 >> 5, q = (k0 >> 3) & 3;
    _Float16 v8[8];
#pragma unroll
    for (int kk = 0; kk < 8; ++kk) {
      float f = (n < 255) ? Ws[(size_t)(k0 + kk) * 255 + n] : 0.f;
      v8[kk] = (_Float16)f;
    }
    *(half8*)&wt[(size_t)(T * 16 + c) * 512 + (q * 16 + r) * 8] = *(half8*)v8;
  } else {                             // value^T: 64 k-rows per block
    const int k0 = (bid - 64) * 64;
#pragma unroll
    for (int j = 0; j < 16; ++j) {
      int e = t + j * 256;             // 0..4095
      int k = k0 + (e >> 6), n = e & 63;
      float f = value[(size_t)k * O + n];
      int T = n >> 4, r = n & 15, kc = k >> 5, q = (k >> 3) & 3, jj = k & 7;
      vt[(size_t)(T * 8 + kc) * 512 + (q * 16 + r) * 8 + jj] = (_Float16)f;
    }
    if (bid == 64 && t == 0) *reg_slot = 0.f;
  }
}

__global__ __launch_bounds__(256, 2) void sdt_main(
    const float* __restrict__ x, const _Float16* __restrict__ wt,
    const _Float16* __restrict__ vt, const float* __restrict__ bs,
    float* __restrict__ out, float* __restrict__ reg_out)
{
  // Overlay: phase 1 x-tile fp16 (16640 B) / phase 2 L_s (16640 B), + P_h.
  __shared__ __align__(16) char smem[16640 + 8960];
  _Float16* xh_s = (_Float16*)smem;              // [16][520]
  float*    L_s  = (float*)smem;                 // [16][260]
  _Float16* P_h  = (_Float16*)(smem + 16640);    // [16][280]
  __shared__ float red_s[4];

  const int t = threadIdx.x, lane = t & 63, w = t >> 6;   // 4 waves
  const int q = lane >> 4, r16 = lane & 15;
  const int R0 = blockIdx.x * 16;

  // ---- issue chunk-0 B-frag loads early (global wt, L2-warm from sdt_pre) ----
  const _Float16* pb = wt + (size_t)(w * 4) * 16 * 512 + lane * 8;  // tiles 4w..4w+3
  half8 Ba[4], Bb[4];
#pragma unroll
  for (int nt = 0; nt < 4; ++nt) Ba[nt] = *(const half8*)(pb + nt * 16 * 512);

  // ---- stage + convert x tile once (coalesced), 16 rows ----
  {
    const int row = t >> 4, l4 = (t & 15) * 4;
    const float* xrow = x + (size_t)(R0 + row) * 512;
#pragma unroll
    for (int i = 0; i < 8; ++i) {
      const int k = l4 + i * 64;
      float4 v = *(const float4*)(xrow + k);
      half4 h = {(_Float16)v.x, (_Float16)v.y, (_Float16)v.z, (_Float16)v.w};
      *(half4*)&xh_s[row * XSTR + k] = h;
    }
  }

  // chunk-1 B-frags in flight across the barrier
#pragma unroll
  for (int nt = 0; nt < 4; ++nt) Bb[nt] = *(const half8*)(pb + nt * 16 * 512 + 512);

  __syncthreads();   // barrier 1: x tile staged

  // ---- K-loop: 16 chunks of K=32, 4 MFMA each, prefetch depth 2 ----
  floatx4 acc[4] = {{0,0,0,0},{0,0,0,0},{0,0,0,0},{0,0,0,0}};
  const int aoff = r16 * XSTR + q * 8;
  half8 A0 = *(const half8*)&xh_s[aoff];
  half8 A1 = *(const half8*)&xh_s[aoff + 32];

#pragma unroll
  for (int cc = 0; cc < 8; ++cc) {
    const int c0 = 2 * cc, c1 = 2 * cc + 1;
#pragma unroll
    for (int nt = 0; nt < 4; ++nt)
      acc[nt] = __builtin_amdgcn_mfma_f32_16x16x32_f16(A0, Ba[nt], acc[nt], 0, 0, 0);
    if (c0 + 2 < 16) {
      A0 = *(const half8*)&xh_s[aoff + (c0 + 2) * 32];
#pragma unroll
      for (int nt = 0; nt < 4; ++nt)
        Ba[nt] = *(const half8*)(pb + nt * 16 * 512 + (c0 + 2) * 512);
    }
#pragma unroll
    for (int nt = 0; nt < 4; ++nt)
      acc[nt] = __builtin_amdgcn_mfma_f32_16x16x32_f16(A1, Bb[nt], acc[nt], 0, 0, 0);
    if (c1 + 2 < 16) {
      A1 = *(const half8*)&xh_s[aoff + (c1 + 2) * 32];
#pragma unroll
      for (int nt = 0; nt < 4; ++nt)
        Bb[nt] = *(const half8*)(pb + nt * 16 * 512 + (c1 + 2) * 512);
    }
  }

  // ---- fused epilogue: bias + sigmoid + reg, all on registers (pre-barrier) ----
  float pv[4][4];
  float rsum = 0.f;
#pragma unroll
  for (int nt = 0; nt < 4; ++nt) {
    const int col = w * 64 + nt * 16 + r16;
    const float b = (col < 255) ? bs[col] : 0.f;
    float csum = 0.f;
#pragma unroll
    for (int r = 0; r < 4; ++r) {
      float p = 1.f / (1.f + __expf(-(acc[nt][r] + b)));
      pv[nt][r] = p;
      csum += __logf(fmaxf(p * (1.f - p), 1e-5f));
    }
    const int dd = 31 - __clz(col + 1);
    rsum += (col < 255) ? csum * (-0.5f / (8192.0f * (float)(1 << dd))) : 0.f;
  }
#pragma unroll
  for (int off = 32; off; off >>= 1) rsum += __shfl_down(rsum, off, 64);

  __syncthreads();   // barrier 2: all xh_s reads done before L_s overlays it

  {
#pragma unroll
    for (int nt = 0; nt < 4; ++nt) {
      const int col = w * 64 + nt * 16 + r16;
#pragma unroll
      for (int r = 0; r < 4; ++r)
        L_s[(q * 4 + r) * LSTR + col] = pv[nt][r];
    }
    if (lane == 0) red_s[w] = rsum;
  }
  __syncthreads();   // barrier 3: probabilities visible to all waves

  if (t == 0)
    atomicAdd(reg_out, red_s[0] + red_s[1] + red_s[2] + red_s[3]);

  // ---- prefetch vt B-frags for phase 2c (latency hides under phase 2b) ----
  half8 VB[8];
  {
    const _Float16* vb = vt + (size_t)(w * 8) * 512 + lane * 8;   // n-tile = w
#pragma unroll
    for (int kc = 0; kc < 8; ++kc) VB[kc] = *(const half8*)(vb + kc * 512);
  }

  // ---- phase 2b: path products, 8 leaves x 2 rows per thread ----
  {
    const int g8 = t & 31, rp = t >> 5;          // rp 0..7, rows rp*2+rr
    const int Lb = g8 * 8;
#pragma unroll
    for (int rr = 0; rr < 2; ++rr) {
      const int row = rp * 2 + rr;
      const float* Lr = &L_s[row * LSTR];
      float pre = 1.f;
#pragma unroll
      for (int dd = 0; dd < 5; ++dd) {
        float p = Lr[(1 << dd) - 1 + (Lb >> (8 - dd))];
        float br = ((Lb >> (7 - dd)) & 1) ? (1.f - p) : p;
        pre *= fmaxf(br, 1e-5f);
      }
      float p5 = Lr[31 + g8];
      float s5a = fmaxf(p5, 1e-5f), s5b = fmaxf(1.f - p5, 1e-5f);
      float p6a = Lr[63 + 2 * g8], p6b = Lr[63 + 2 * g8 + 1];
      float p7v[4];
#pragma unroll
      for (int m = 0; m < 4; ++m) p7v[m] = Lr[127 + 4 * g8 + m];
      _Float16 ph[8];
#pragma unroll
      for (int j = 0; j < 8; ++j) {
        float s5 = (j & 4) ? s5b : s5a;
        float p6 = (j & 4) ? p6b : p6a;
        float s6 = fmaxf((j & 2) ? (1.f - p6) : p6, 1e-5f);
        float p7 = p7v[j >> 1];
        float s7 = fmaxf((j & 1) ? (1.f - p7) : p7, 1e-5f);
        ph[j] = (_Float16)(pre * s5 * s6 * s7);
      }
      *(half8*)&P_h[row * PSTR + Lb] = *(half8*)ph;
    }
  }
  __syncthreads();   // barrier 4: P_h ready

  // ---- phase 2c: out[16][64] = P @ value via fp16 MFMA ----
  {
    floatx4 C = {0, 0, 0, 0};
    const _Float16* pa = &P_h[r16 * PSTR + q * 8];
#pragma unroll
    for (int kc = 0; kc < 8; ++kc) {
      half8 A8 = *(const half8*)(pa + kc * 32);
      C = __builtin_amdgcn_mfma_f32_16x16x32_f16(A8, VB[kc], C, 0, 0, 0);
    }
    const int colo = w * 16 + r16;
#pragma unroll
    for (int r = 0; r < 4; ++r)
      out[(size_t)(R0 + q * 4 + r) * O + colo] = C[r];
  }
}

extern "C" void kernel_launch(void* const* d_in, const int* in_sizes, int n_in,
                              void* d_out, int out_size, void* d_ws, size_t ws_size,
                              hipStream_t stream) {
  const float* x     = (const float*)d_in[0];
  const float* Ws    = (const float*)d_in[1];
  const float* bs    = (const float*)d_in[2];
  const float* value = (const float*)d_in[3];
  float* outp = (float*)d_out;
  float* reg_slot = outp + (size_t)8192 * O;          // index 524288
  _Float16* wt = (_Float16*)d_ws;                     // frag-major W^T fp16, 256 KB
  _Float16* vt = wt + 256 * 512;                      // frag-major value^T fp16, 32 KB

  sdt_pre<<<68, 256, 0, stream>>>(Ws, value, wt, vt, reg_slot);
  sdt_main<<<512, 256, 0, stream>>>(x, wt, vt, bs, outp, reg_slot);
}